// Round 14
// baseline (357.626 us; speedup 1.0000x reference)
//
#include <hip/hip_runtime.h>
#include <hip/hip_bf16.h>
#include <math.h>

// ---------------------------------------------------------------------------
// DeepDCNN: emb-gather -> 4x [grouped full-conv + pair-fold + ordered top-k +
// tanh] -> FC.  All fp32.
// CROSS-LAYER FUSION: L2 group j2 consumes exactly L1 groups {2j2,2j2+1};
// L4 group j4 consumes exactly L3 groups {2j4,2j4+1}.  So K1 = L1+L2 in one
// block through LDS (Z1 never hits HBM), K2 = L3+L4 (Z3 never hits HBM).
// Top-k = wave-level bitwise radix select (ballot + s_bcnt), 4-ary for L1
// chains / binary for conv chains (measured-best per R10-R13 matrix).
// L1/L3 selects scatter DIRECTLY into the padded LDS rows the next conv
// reads (stage == destination, no copy).
// ---------------------------------------------------------------------------

#if defined(__has_builtin)
#if __has_builtin(__builtin_amdgcn_ballot_w64)
#define BALLOT64(expr) __builtin_amdgcn_ballot_w64(expr)
#endif
#endif
#ifndef BALLOT64
#define BALLOT64(expr) __ballot(expr)
#endif

__device__ __forceinline__ unsigned f2ord(float f) {
    unsigned u = __float_as_uint(f);
    return (u & 0x80000000u) ? ~u : (u | 0x80000000u);
}
__device__ __forceinline__ float ord2f(unsigned key) {
    unsigned u = (key & 0x80000000u) ? (key & 0x7fffffffu) : ~key;
    return __uint_as_float(u);
}
// tanh via exp + hw rcp: 1 - 2*rcp(e^{2x}+1).  |err| ~1e-7.  Keys are
// pre-tanh so selection ordering is unaffected.
__device__ __forceinline__ float tanh_fast(float x) {
    float e = __expf(2.f * x);
    return 1.f - 2.f * __builtin_amdgcn_rcpf(e + 1.f);
}
__device__ __forceinline__ int mbcnt64(unsigned long long m) {
    return __builtin_amdgcn_mbcnt_hi((unsigned)(m >> 32),
           __builtin_amdgcn_mbcnt_lo((unsigned)m, 0u));
}

// wave-total count of keys >= t  (1 v_cmp -> SGPR pair; s_bcnt pipelines
// under the next v_cmp burst)
template<int CH>
__device__ __forceinline__ int count_ge(const unsigned* keys, unsigned t) {
    int c = 0;
    #pragma unroll
    for (int i = 0; i < CH; ++i)
        c += __popcll(BALLOT64((keys[i] >= t)));
    return c;
}

// ---- compaction + tanh scatter into stage; optional coalesced copy-out ---
// T = threshold key (low bits may be zeroed by early exit; then ALL bucket
// members are kept).  Stable (earliest ties), order-preserving.
// If out == nullptr, stage IS the final destination (LDS row) — no copy.
template<int CH>
__device__ __forceinline__ void select_finish(const unsigned* keys, unsigned T,
                                              int k, float* stage,
                                              float* __restrict__ out)
{
    int g = 0, e = 0;
    #pragma unroll
    for (int i = 0; i < CH; ++i) { g += (keys[i] > T); e += (keys[i] == T); }

    int gtBefore = 0, eqBefore = 0, totG = 0;
    #pragma unroll
    for (int b = 0; b < 5; ++b) {     // CH <= 17 < 32 -> 5 bits
        unsigned long long mg = BALLOT64((((g >> b) & 1) != 0));
        unsigned long long me = BALLOT64((((e >> b) & 1) != 0));
        gtBefore += mbcnt64(mg) << b;
        eqBefore += mbcnt64(me) << b;
        totG     += __popcll(mg) << b;
    }
    const int needTies = k - totG;    // # of ==T to keep (earliest)

    int gRun = 0, eRun = 0;
    #pragma unroll
    for (int i = 0; i < CH; ++i) {
        const unsigned key = keys[i];
        const bool isG = key > T;
        const bool isE = key == T;
        const int eIdx = eqBefore + eRun;
        const int dst = gtBefore + gRun + min(eIdx, needTies);
        if (isG || (isE && eIdx < needTies))
            stage[dst] = tanh_fast(ord2f(key));
        gRun += isG; eRun += isE;
    }
    if (out) {  // coalesced float4 copy-out (k % 4 == 0, 16B-aligned)
        const int lane = threadIdx.x & 63;
        float4* o4 = (float4*)out;
        const float4* s4 = (const float4*)stage;
        for (int i = lane; i < (k >> 2); i += 64)
            o4[i] = s4[i];
    }
}

// ---- N-row exact top-k, RADIX-ary interleaved chains w/ early exit -------
// Lane holds contiguous chunk [lane*CH, ...) of each row as order-keys in
// regs; invalid slots MUST be 0 (k < real element count in every layer, so
// padding can never enter the kept set).
template<int N, int CH, int RADIX>
__device__ void wave_selectN(const unsigned (*keys)[CH], int k,
                             float* const* stages, float* const* outs)
{
    unsigned p[N];
    int above[N], buck[N];
    #pragma unroll
    for (int n = 0; n < N; ++n) { p[n] = 0u; above[n] = 0; buck[n] = 64 * CH; }

    unsigned doneMask = 0;
    const unsigned allDone = (1u << N) - 1u;

    if (RADIX == 4) {
        #pragma unroll 1
        for (int pos = 15; pos >= 0; --pos) {
            #pragma unroll
            for (int n = 0; n < N; ++n) {
                if (!((doneMask >> n) & 1u)) {    // wave-uniform branch
                    const int sh = 2 * pos;
                    const unsigned t1 = p[n] | (1u << sh);
                    const unsigned t2 = p[n] | (2u << sh);
                    const unsigned t3 = p[n] | (3u << sh);
                    const int c1 = count_ge<CH>(keys[n], t1);
                    const int c2 = count_ge<CH>(keys[n], t2);
                    const int c3 = count_ge<CH>(keys[n], t3);
                    const int rem = k - above[n];
                    if (c3 - above[n] >= rem) {
                        p[n] = t3; buck[n] = c3 - above[n];
                    } else if (c2 - above[n] >= rem) {
                        p[n] = t2; buck[n] = c2 - c3; above[n] = c3;
                    } else if (c1 - above[n] >= rem) {
                        p[n] = t1; buck[n] = c1 - c2; above[n] = c2;
                    } else {
                        buck[n] -= (c1 - above[n]); above[n] = c1;
                    }
                    if (buck[n] == k - above[n]) doneMask |= (1u << n);
                }
            }
            if (doneMask == allDone) break;
        }
    } else {
        #pragma unroll 1
        for (int pos = 31; pos >= 0; --pos) {
            #pragma unroll
            for (int n = 0; n < N; ++n) {
                if (!((doneMask >> n) & 1u)) {    // wave-uniform branch
                    const unsigned t = p[n] | (1u << pos);
                    const int c = count_ge<CH>(keys[n], t);
                    const int inb = c - above[n];
                    const int rem = k - above[n];
                    if (inb >= rem) { p[n] = t; buck[n] = inb; }
                    else            { above[n] += inb; buck[n] -= inb; }
                    if (buck[n] == k - above[n]) doneMask |= (1u << n);
                }
            }
            if (doneMask == allDone) break;
        }
    }
    #pragma unroll
    for (int n = 0; n < N; ++n)
        select_finish<CH>(keys[n], p[n], k, stages[n], outs[n]);
}

// ---------------------------------------------------------------------------
// K1: L1 + L2 fused.  grid (16 j2, 64 b), block 640 = 10 waves.
//  L1: wave w -> group jj=w/5 (local 0..1), filters q=w%5 and q+5 (dual
//      4-ary chains); selects scatter into padded LDS rows z1[20][840].
//  L2: waves 0..6, filters 2w, 2w+1 (dual binary chains) -> Z2 (global).
//  Z1 never touches HBM.
// ---------------------------------------------------------------------------
#define L1RW 1100   // padded gather row width
#define Z1W  840    // 4 zero-pad + 768 data + zero tail (>= 64*13+4 = 836)

__global__ __launch_bounds__(640) void l12_fused(
    const int* __restrict__ tokens, const float* __restrict__ emb,
    const float* __restrict__ W1, const float* __restrict__ B1,
    const float* __restrict__ W2, const float* __restrict__ B2,
    float* __restrict__ Z2)
{
    const int j2 = blockIdx.x;   // 0..15
    const int b  = blockIdx.y;   // 0..63
    const int t  = threadIdx.x;
    const int wav  = __builtin_amdgcn_readfirstlane(t >> 6);  // 0..9
    const int lane = t & 63;

    __shared__ __align__(16) float xr[4][L1RW];   // 17.6 KB (reused as L2 stage)
    __shared__ __align__(16) float z1[20][Z1W];   // 67.2 KB

    // gather emb channels 4*j2 .. 4*j2+3 (float4 per token); zero pads
    const float4* emb4 = (const float4*)emb;   // E=64 floats = 16 float4
    for (int i = t; i < L1RW; i += 640) {
        int s = i - 6;
        float4 v = make_float4(0.f, 0.f, 0.f, 0.f);
        if (s >= 0 && s < 1024) {
            int tok = tokens[b * 1024 + s];
            v = emb4[(size_t)tok * 16 + j2];
        }
        xr[0][i] = v.x; xr[1][i] = v.y; xr[2][i] = v.z; xr[3][i] = v.w;
    }
    // zero z1 pad columns [0,4) and [772,Z1W)
    {
        const int PERROW = 4 + (Z1W - 772);
        for (int i = t; i < 20 * PERROW; i += 640) {
            int r = i / PERROW, p = i - r * PERROW;
            z1[r][(p < 4) ? p : (772 + p - 4)] = 0.f;
        }
    }
    __syncthreads();

    // ---- L1 ----
    {
        const int jj = wav / 5;              // local pair-group 0..1
        const int q  = wav % 5;
        const int jg = 2 * j2 + jj;          // global L1 pair-group 0..31
        const int beg = lane * 17;

        float x0[23], x1[23];
        #pragma unroll
        for (int i = 0; i < 23; ++i) {
            x0[i] = xr[2 * jj][beg + i];
            x1[i] = xr[2 * jj + 1][beg + i];
        }

        unsigned keys[2][17];
        float* stages[2];
        float* outs[2] = { nullptr, nullptr };
        #pragma unroll
        for (int n = 0; n < 2; ++n) {
            const int f = q + 5 * n;
            float wa[7], wb[7];
            #pragma unroll
            for (int k2 = 0; k2 < 7; ++k2) {
                wa[k2] = W1[(2 * jg * 10 + f) * 7 + k2];
                wb[k2] = W1[((2 * jg + 1) * 10 + f) * 7 + k2];
            }
            const float bias = B1[2 * jg * 10 + f] + B1[(2 * jg + 1) * 10 + f];
            #pragma unroll
            for (int i = 0; i < 17; ++i) {
                float acc = bias;
                #pragma unroll
                for (int k2 = 0; k2 < 7; ++k2)
                    acc += x0[i + k2] * wa[k2] + x1[i + k2] * wb[k2];
                keys[n][i] = (beg + i < 1030) ? f2ord(acc) : 0u;
            }
            stages[n] = &z1[jj * 10 + f][4];   // scatter directly into LDS row
        }
        wave_selectN<2, 17, 4>(keys, 768, stages, outs);
    }
    __syncthreads();

    // ---- L2 ----
    if (wav < 7) {
        const int f0 = 2 * wav;
        const int base = lane * 13;
        float acc0[13], acc1[13];
        {
            const float b0 = B2[2 * j2 * 14 + f0]     + B2[(2 * j2 + 1) * 14 + f0];
            const float b1 = B2[2 * j2 * 14 + f0 + 1] + B2[(2 * j2 + 1) * 14 + f0 + 1];
            #pragma unroll
            for (int i = 0; i < 13; ++i) { acc0[i] = b0; acc1[i] = b1; }
        }
        #pragma unroll 1
        for (int r = 0; r < 20; ++r) {
            const int h = r / 10, c = r - 10 * (r / 10);
            float win[17];
            #pragma unroll
            for (int p = 0; p < 17; ++p) win[p] = z1[r][base + p];
            const float* Wp = W2 + ((size_t)((2 * j2 + h) * 14 + f0) * 10 + c) * 5;
            #pragma unroll
            for (int k2 = 0; k2 < 5; ++k2) {
                const float w0 = Wp[k2];
                const float w1 = Wp[50 + k2];          // next filter: +IPG*K
                #pragma unroll
                for (int i = 0; i < 13; ++i) {
                    acc0[i] = fmaf(win[i + k2], w0, acc0[i]);
                    acc1[i] = fmaf(win[i + k2], w1, acc1[i]);
                }
            }
        }
        unsigned keys[2][13];
        #pragma unroll
        for (int i = 0; i < 13; ++i) {
            keys[0][i] = (base + i < 772) ? f2ord(acc0[i]) : 0u;
            keys[1][i] = (base + i < 772) ? f2ord(acc1[i]) : 0u;
        }
        float* st = &xr[0][0] + wav * 512;     // xr dead after L1 -> reuse
        float* stages[2] = { st, st };
        const size_t orow = (size_t)b * 224 + (size_t)j2 * 14;
        float* outs[2] = { Z2 + (orow + f0) * 512, Z2 + (orow + f0 + 1) * 512 };
        wave_selectN<2, 13, 2>(keys, 512, stages, outs);
    }
}

// ---------------------------------------------------------------------------
// K2: L3 + L4 fused.  grid (4 j4, 64 b), block 704 = 11 waves.
//  Two phases: stage 28 Z2 rows for L3 group j3 = 2*j4+ph, conv+select
//  (waves 0..8, dual binary chains) into padded z3 rows.  Then L4 over all
//  36 z3 rows (11 waves x 2 filters) -> Z4 (global).  Z3 never hits HBM.
// ---------------------------------------------------------------------------
#define X2W 580    // 4 zero-pad + 512 + tail (= 64*9+4)
#define Z3W 324    // 2 zero-pad + 256 + zero tail (>= 64*5+2 = 322)

__global__ __launch_bounds__(704) void l34_fused(
    const float* __restrict__ Z2, const float* __restrict__ W3,
    const float* __restrict__ B3, const float* __restrict__ W4,
    const float* __restrict__ B4, float* __restrict__ Z4)
{
    const int j4 = blockIdx.x;   // 0..3
    const int b  = blockIdx.y;   // 0..63
    const int t  = threadIdx.x;
    const int wav  = __builtin_amdgcn_readfirstlane(t >> 6);  // 0..10
    const int lane = t & 63;

    __shared__ __align__(16) float x2[28][X2W];   // 65 KB (reused as L4 stage)
    __shared__ __align__(16) float z3[36][Z3W];   // 46.7 KB

    // zero z3 pad columns [0,2) and [258,Z3W)
    {
        const int PERROW = 2 + (Z3W - 258);
        for (int i = t; i < 36 * PERROW; i += 704) {
            int r = i / PERROW, p = i - r * PERROW;
            z3[r][(p < 2) ? p : (258 + p - 2)] = 0.f;
        }
    }

    #pragma unroll 1
    for (int ph = 0; ph < 2; ++ph) {
        if (ph) __syncthreads();             // protect x2 reuse
        const float* Zb = Z2 + ((size_t)b * 224 + (size_t)(4 * j4 + 2 * ph) * 14) * 512;
        for (int idx = t; idx < 28 * X2W; idx += 704) {
            int r = idx / X2W, p = idx - r * X2W;
            int sg = p - 4;
            x2[r][p] = (sg >= 0 && sg < 512) ? Zb[(size_t)r * 512 + sg] : 0.f;
        }
        __syncthreads();

        if (wav < 9) {
            const int f0 = 2 * wav;
            const int j3 = 2 * j4 + ph;
            const int base = lane * 9;
            float acc0[9], acc1[9];
            {
                const float b0 = B3[2 * j3 * 18 + f0]     + B3[(2 * j3 + 1) * 18 + f0];
                const float b1 = B3[2 * j3 * 18 + f0 + 1] + B3[(2 * j3 + 1) * 18 + f0 + 1];
                #pragma unroll
                for (int i = 0; i < 9; ++i) { acc0[i] = b0; acc1[i] = b1; }
            }
            #pragma unroll 1
            for (int r = 0; r < 28; ++r) {
                const int h = r / 14, c = r - 14 * (r / 14);
                float win[13];
                #pragma unroll
                for (int p = 0; p < 13; ++p) win[p] = x2[r][base + p];
                const float* Wp = W3 + ((size_t)((2 * j3 + h) * 18 + f0) * 14 + c) * 5;
                #pragma unroll
                for (int k2 = 0; k2 < 5; ++k2) {
                    const float w0 = Wp[k2];
                    const float w1 = Wp[70 + k2];      // next filter: +IPG*K
                    #pragma unroll
                    for (int i = 0; i < 9; ++i) {
                        acc0[i] = fmaf(win[i + k2], w0, acc0[i]);
                        acc1[i] = fmaf(win[i + k2], w1, acc1[i]);
                    }
                }
            }
            unsigned keys[2][9];
            #pragma unroll
            for (int i = 0; i < 9; ++i) {
                keys[0][i] = (base + i < 516) ? f2ord(acc0[i]) : 0u;
                keys[1][i] = (base + i < 516) ? f2ord(acc1[i]) : 0u;
            }
            float* stages[2] = { &z3[18 * ph + f0][2], &z3[18 * ph + f0 + 1][2] };
            float* outs[2] = { nullptr, nullptr };
            wave_selectN<2, 9, 2>(keys, 256, stages, outs);
        }
    }
    __syncthreads();

    // ---- L4 (all 11 waves) ----
    {
        const int f0 = 2 * wav;
        const int base = lane * 5;
        float acc0[5], acc1[5];
        {
            const float b0 = B4[2 * j4 * 22 + f0]     + B4[(2 * j4 + 1) * 22 + f0];
            const float b1 = B4[2 * j4 * 22 + f0 + 1] + B4[(2 * j4 + 1) * 22 + f0 + 1];
            #pragma unroll
            for (int i = 0; i < 5; ++i) { acc0[i] = b0; acc1[i] = b1; }
        }
        #pragma unroll 1
        for (int r = 0; r < 36; ++r) {
            const int h = r / 18, c = r - 18 * (r / 18);
            float win[7];
            #pragma unroll
            for (int p = 0; p < 7; ++p) win[p] = z3[r][base + p];
            const float* Wp = W4 + ((size_t)((2 * j4 + h) * 22 + f0) * 18 + c) * 3;
            #pragma unroll
            for (int k2 = 0; k2 < 3; ++k2) {
                const float w0 = Wp[k2];
                const float w1 = Wp[54 + k2];          // next filter: +IPG*K
                #pragma unroll
                for (int i = 0; i < 5; ++i) {
                    acc0[i] = fmaf(win[i + k2], w0, acc0[i]);
                    acc1[i] = fmaf(win[i + k2], w1, acc1[i]);
                }
            }
        }
        unsigned keys[2][5];
        #pragma unroll
        for (int i = 0; i < 5; ++i) {
            keys[0][i] = (base + i < 258) ? f2ord(acc0[i]) : 0u;
            keys[1][i] = (base + i < 258) ? f2ord(acc1[i]) : 0u;
        }
        float* st = &x2[0][0] + wav * 4;       // x2 dead -> tiny k=4 stage
        float* stages[2] = { st, st };
        const size_t orow = (size_t)b * 88 + (size_t)j4 * 22;
        float* outs[2] = { Z4 + (orow + f0) * 4, Z4 + (orow + f0 + 1) * 4 };
        wave_selectN<2, 5, 2>(keys, 4, stages, outs);
    }
}

// ---------------------------------------------------------------------------
// FC: (64,352) @ (6,352)^T + b
// ---------------------------------------------------------------------------
__global__ __launch_bounds__(192) void fc_kernel(
    const float* __restrict__ Z, const float* __restrict__ Wf,
    const float* __restrict__ bf, float* __restrict__ out)
{
    int g = blockIdx.x * blockDim.x + threadIdx.x;
    if (g >= 64 * 6) return;
    int b = g / 6, c = g % 6;
    float acc = bf[c];
    const float* zr = Z + b * 352;
    const float* wr = Wf + c * 352;
    for (int i = 0; i < 352; ++i) acc += zr[i] * wr[i];
    out[g] = acc;
}

extern "C" void kernel_launch(void* const* d_in, const int* in_sizes, int n_in,
                              void* d_out, int out_size, void* d_ws, size_t ws_size,
                              hipStream_t stream)
{
    const int*   tokens = (const int*)  d_in[0];
    const float* emb    = (const float*)d_in[1];
    const float* w1     = (const float*)d_in[2];
    const float* b1     = (const float*)d_in[3];
    const float* w2     = (const float*)d_in[4];
    const float* b2     = (const float*)d_in[5];
    const float* w3     = (const float*)d_in[6];
    const float* b3     = (const float*)d_in[7];
    const float* w4     = (const float*)d_in[8];
    const float* b4     = (const float*)d_in[9];
    const float* fcw    = (const float*)d_in[10];
    const float* fcb    = (const float*)d_in[11];
    float* out = (float*)d_out;
    float* ws  = (float*)d_ws;

    // workspace (floats): only Z2 and Z4 exist now.
    //  Z2 [0,       7340032)   64*224*512  (29 MB)
    //  Z4 [7340032, 7362560)   64*88*4
    float* Z2 = ws;
    float* Z4 = ws + 7340032;

    l12_fused<<<dim3(16, 64), 640, 0, stream>>>(tokens, emb, w1, b1, w2, b2, Z2);
    l34_fused<<<dim3(4, 64), 704, 0, stream>>>(Z2, w3, b3, w4, b4, Z4);
    fc_kernel<<<2, 192, 0, stream>>>(Z4, fcw, fcb, out);
}